// Round 11
// baseline (4181.577 us; speedup 1.0000x reference)
//
#include <hip/hip_runtime.h>
#include <math.h>

// Problem constants: D=3, H=64, WIN=8, OUT=32, B=128, T=129
#define BB 128
#define TT 129
#define NSTEP 128
#define NW 16
#define WINW 8
#define OUTD 32

typedef _Float16 h2_t __attribute__((ext_vector_type(2)));

__device__ __forceinline__ float fast_rcp(float v){ return __builtin_amdgcn_rcpf(v); }
__device__ __forceinline__ float softplus_f(float v){ return fmaxf(v,0.f)+__logf(1.f+__expf(-fabsf(v))); }
__device__ __forceinline__ float sigmoid_f(float v){ return fast_rcp(1.f+__expf(-v)); }
__device__ __forceinline__ float tanh_f(float v){
    float ax=fminf(fabsf(v),15.f); float e=__expf(2.f*ax);
    float r=1.f-2.f*fast_rcp(e+1.f); return copysignf(r,v);
}
__device__ __forceinline__ float pack2(float a,float b){
    h2_t h; h.x=(_Float16)a; h.y=(_Float16)b; return __builtin_bit_cast(float,h);
}
__device__ __forceinline__ float dot2c(float wc,float ac,float acc){
    return __builtin_amdgcn_fdot2(__builtin_bit_cast(h2_t,wc),__builtin_bit_cast(h2_t,ac),acc,false);
}
__device__ __forceinline__ float dot2q(float4 wq,float4 aq,float acc){
    acc=dot2c(wq.x,aq.x,acc); acc=dot2c(wq.y,aq.y,acc);
    acc=dot2c(wq.z,aq.z,acc); acc=dot2c(wq.w,aq.w,acc); return acc;
}
__device__ __forceinline__ float4 packrow8(const float4* p, int k){
    float4 a=p[2*k], c=p[2*k+1];
    float4 r; r.x=pack2(a.x,a.y); r.y=pack2(a.z,a.w); r.z=pack2(c.x,c.y); r.w=pack2(c.z,c.w);
    return r;
}
#define DOT4(acc,Wv,Av) acc += (Wv).x*(Av).x + (Wv).y*(Av).y + (Wv).z*(Av).z + (Wv).w*(Av).w
#define PIN4(q) asm volatile("" : "+v"((q).x), "+v"((q).y), "+v"((q).z), "+v"((q).w))

// ONE WAVE per element: zero barriers, zero shuffles. V0/V1 rows in registers
// (192 VGPR, 1 wave/SIMD cap = 512), V2 + R in LDS fp16 with rotated-iteration
// bank spreading. S7 is fully lane-local (V2 rows l, 64+l, 128+l per lane).
__global__ __launch_bounds__(64, 1)
void ncde_solve(const float* __restrict__ ts, const float* __restrict__ x,
                const float* __restrict__ W0, const float* __restrict__ b0,
                const float* __restrict__ W1, const float* __restrict__ b1,
                const float* __restrict__ W2, const float* __restrict__ b2,
                const float* __restrict__ V0, const float* __restrict__ c0,
                const float* __restrict__ V1, const float* __restrict__ c1,
                const float* __restrict__ V2, const float* __restrict__ c2,
                const float* __restrict__ R, const float* __restrict__ rb,
                float* __restrict__ out)
{
    const int b = blockIdx.x;
    const int l = threadIdx.x;
    const int dl = l & 15;   // rotation offset for 16-chunk rows
    const int dlR = l & 7;   // rotation offset for 8-chunk rows (R)

    __shared__ __align__(16) float4 v2L[192*16];   // 48KB V2 fp16, row-major
    __shared__ __align__(16) float4 rL[OUTD*8];    // 4KB R fp16, row-major
    __shared__ __align__(16) float4 yaL[8], y2aL[8];      // y: 64 halves
    __shared__ __align__(16) float4 a0L[16], a1L[16];     // 128 halves each
    __shared__ __align__(16) float4 mL[24];               // 192 halves
    __shared__ __align__(16) float4 u0L[3][16], u1L[3][16];
    __shared__ float slopesSh[NW][6];
    __shared__ float dtsSh[NSTEP];
    __shared__ __align__(16) float scrA[128], scrB[128];  // fp32 init scratch

    // ---- register weights: V0 rows 2l,2l+1 (16 f4), V1 rows 2l,2l+1 (32 f4) ----
    float4 v0r[2][8];
    float4 v1r[2][16];
    #pragma unroll
    for (int r=0;r<2;r++){
        const float4* p = (const float4*)(V0 + (2*l+r)*64);
        #pragma unroll
        for (int k=0;k<8;k++) v0r[r][k] = packrow8(p,k);
    }
    #pragma unroll
    for (int r=0;r<2;r++){
        const float4* p = (const float4*)(V1 + (2*l+r)*128);
        #pragma unroll
        for (int k=0;k<16;k++) v1r[r][k] = packrow8(p,k);
    }
    #pragma unroll
    for (int r=0;r<2;r++){
        #pragma unroll
        for (int k=0;k<8;k++) PIN4(v0r[r][k]);
        #pragma unroll
        for (int k=0;k<16;k++) PIN4(v1r[r][k]);
    }

    // ---- stage V2 rows l, 64+l, 128+l and R rows (lanes<32) into LDS ----
    #pragma unroll
    for (int rr=0;rr<3;rr++){
        const int r = rr*64 + l;
        const float4* src = (const float4*)(V2 + r*128);
        #pragma unroll
        for (int c=0;c<16;c++) v2L[r*16+c] = packrow8(src,c);
    }
    if (l < OUTD){
        const float4* src = (const float4*)(R + l*64);
        #pragma unroll
        for (int c=0;c<8;c++) rL[l*8+c] = packrow8(src,c);
    }

    const float c00=c0[2*l], c01=c0[2*l+1];
    const float c10=c1[2*l], c11=c1[2*l+1];
    const float c20=c2[l],  c21=c2[64+l], c22=c2[128+l];
    const float rbp = rb[l & 31];

    const float* tsb = ts + b*TT;
    for (int i=l;i<NSTEP;i+=64) dtsSh[i] = tsb[i+1]-tsb[i];

    // ---- log-signature slopes (lanes 0..15) ----
    if (l < NW) {
        const int w = l;
        const float* xs = x + (size_t)(b*TT + w*WINW)*3;
        float x0c[3] = {xs[0], xs[1], xs[2]};
        float prev[3] = {x0c[0], x0c[1], x0c[2]};
        float am01=0.f, am02=0.f, am12=0.f, am10=0.f, am20=0.f, am21=0.f;
        #pragma unroll
        for (int k=0;k<WINW;k++) {
            float cur[3] = {xs[(k+1)*3+0], xs[(k+1)*3+1], xs[(k+1)*3+2]};
            float rel[3], dv[3];
            #pragma unroll
            for (int c=0;c<3;c++){ rel[c]=prev[c]-x0c[c]; dv[c]=cur[c]-prev[c]; }
            am01 += rel[0]*dv[1]; am10 += rel[1]*dv[0];
            am02 += rel[0]*dv[2]; am20 += rel[2]*dv[0];
            am12 += rel[1]*dv[2]; am21 += rel[2]*dv[1];
            prev[0]=cur[0]; prev[1]=cur[1]; prev[2]=cur[2];
        }
        const float invden = 1.f/(tsb[(w+1)*WINW] - tsb[w*WINW]);
        slopesSh[w][0] = (prev[0]-x0c[0])*invden;
        slopesSh[w][1] = (prev[1]-x0c[1])*invden;
        slopesSh[w][2] = (prev[2]-x0c[2])*invden;
        slopesSh[w][3] = 0.5f*(am01-am10)*invden;
        slopesSh[w][4] = 0.5f*(am02-am20)*invden;
        slopesSh[w][5] = 0.5f*(am12-am21)*invden;
    }

    // ---- h0 = init_mlp(x[b,0,:]) (fp32, single wave: LDS in-order, no barriers) ----
    float y;
    {
        const float xv0 = x[(size_t)b*TT*3+0];
        const float xv1 = x[(size_t)b*TT*3+1];
        const float xv2 = x[(size_t)b*TT*3+2];
        #pragma unroll
        for (int r=0;r<2;r++){
            const int row = 2*l+r;
            scrA[row] = softplus_f(b0[row] + W0[row*3]*xv0 + W0[row*3+1]*xv1 + W0[row*3+2]*xv2);
        }
        #pragma unroll
        for (int r=0;r<2;r++){
            const int row = 2*l+r;
            float acc = b1[row];
            const float4* wr = (const float4*)(W1 + row*128);
            #pragma unroll 8
            for (int k=0;k<32;k++){ float4 wv=wr[k]; float4 av=((const float4*)scrA)[k]; DOT4(acc,wv,av); }
            scrB[row] = softplus_f(acc);
        }
        float acc = b2[l];
        const float4* wr = (const float4*)(W2 + l*128);
        #pragma unroll 8
        for (int k=0;k<32;k++){ float4 wv=wr[k]; float4 av=((const float4*)scrB)[k]; DOT4(acc,wv,av); }
        y = acc;
        ((_Float16*)yaL)[l] = (_Float16)y;
    }

    float k1 = 0.f;

    // ---- F(y): zero barriers; rotated LDS reads for V2; V0/V1 from registers ----
    auto Feval = [&](const float4* yIn, bool first, float dt,
                     float s0,float s1,float s2,float s3,float s4,float s5) {
        float sg0a,sg0b,sg1a,sg1b,mm0,mm1,mm2,dt0,dt1,dt2;
        // S1: z0 = V0@y + c0 (rows 2l,2l+1; y broadcast)
        {
            float zA0=0,zB0=0,zA1=0,zB1=0;
            #pragma unroll
            for (int j=0;j<4;j++){ float4 a=yIn[j]; zA0=dot2q(v0r[0][j],a,zA0); zA1=dot2q(v0r[1][j],a,zA1); }
            #pragma unroll
            for (int j=4;j<8;j++){ float4 a=yIn[j]; zB0=dot2q(v0r[0][j],a,zB0); zB1=dot2q(v0r[1][j],a,zB1); }
            float z0=zA0+zB0+c00, z1=zA1+zB1+c01;
            sg0a=sigmoid_f(z0); sg0b=sigmoid_f(z1);
            ((float*)a0L)[l] = pack2(softplus_f(z0), softplus_f(z1));
        }
        // S2: z1 = V1@a0 + c1 (rows 2l,2l+1; a0 broadcast)
        {
            float zA0=0,zB0=0,zA1=0,zB1=0;
            #pragma unroll
            for (int j=0;j<8;j++){  float4 a=a0L[j]; zA0=dot2q(v1r[0][j],a,zA0); zA1=dot2q(v1r[1][j],a,zA1); }
            #pragma unroll
            for (int j=8;j<16;j++){ float4 a=a0L[j]; zB0=dot2q(v1r[0][j],a,zB0); zB1=dot2q(v1r[1][j],a,zB1); }
            float z0=zA0+zB0+c10, z1=zA1+zB1+c11;
            sg1a=sigmoid_f(z0); sg1b=sigmoid_f(z1);
            ((float*)a1L)[l] = pack2(softplus_f(z0), softplus_f(z1));
        }
        // S3: z2 = V2@a1 + c2 (rows l,64+l,128+l; rotated LDS reads)
        {
            float zA0=0,zB0=0,zA1=0,zB1=0,zA2=0,zB2=0;
            #pragma unroll
            for (int j=0;j<16;j++){
                const int c = (j + dl) & 15;
                float4 av = a1L[c];
                float4 w0 = v2L[l*16 + c];
                float4 w1 = v2L[(64+l)*16 + c];
                float4 w2 = v2L[(128+l)*16 + c];
                if (j<8){ zA0=dot2q(w0,av,zA0); zA1=dot2q(w1,av,zA1); zA2=dot2q(w2,av,zA2); }
                else    { zB0=dot2q(w0,av,zB0); zB1=dot2q(w1,av,zB1); zB2=dot2q(w2,av,zB2); }
            }
            float z0=zA0+zB0+c20, z1=zA1+zB1+c21, z2=zA2+zB2+c22;
            mm0=tanh_f(z0); mm1=tanh_f(z1); mm2=tanh_f(z2);
            dt0=1.f-mm0*mm0; dt1=1.f-mm1*mm1; dt2=1.f-mm2*mm2;
            _Float16* mh = (_Float16*)mL;
            mh[l]=(_Float16)mm0; mh[64+l]=(_Float16)mm1; mh[128+l]=(_Float16)mm2;
        }
        // S4: u0[d] = sig0 * (V0 @ m[d]) (V0 regs; m broadcast)
        {
            float t00=0,t01=0,t02=0,t10=0,t11=0,t12=0;   // t{row}{dir}
            #pragma unroll
            for (int j=0;j<8;j++){
                float4 m0v=mL[j], m1v=mL[8+j], m2v=mL[16+j];
                t00=dot2q(v0r[0][j],m0v,t00); t01=dot2q(v0r[0][j],m1v,t01); t02=dot2q(v0r[0][j],m2v,t02);
                t10=dot2q(v0r[1][j],m0v,t10); t11=dot2q(v0r[1][j],m1v,t11); t12=dot2q(v0r[1][j],m2v,t12);
            }
            ((float*)&u0L[0][0])[l]=pack2(sg0a*t00, sg0b*t10);
            ((float*)&u0L[1][0])[l]=pack2(sg0a*t01, sg0b*t11);
            ((float*)&u0L[2][0])[l]=pack2(sg0a*t02, sg0b*t12);
        }
        // S5: u1[d] = sig1 * (V1 @ u0[d]) (V1 regs; u0 broadcast)
        {
            float t00=0,t01=0,t02=0,t10=0,t11=0,t12=0;
            #pragma unroll
            for (int j=0;j<16;j++){
                float4 q0=u0L[0][j], q1=u0L[1][j], q2=u0L[2][j];
                t00=dot2q(v1r[0][j],q0,t00); t01=dot2q(v1r[0][j],q1,t01); t02=dot2q(v1r[0][j],q2,t02);
                t10=dot2q(v1r[1][j],q0,t10); t11=dot2q(v1r[1][j],q1,t11); t12=dot2q(v1r[1][j],q2,t12);
            }
            ((float*)&u1L[0][0])[l]=pack2(sg1a*t00, sg1b*t10);
            ((float*)&u1L[1][0])[l]=pack2(sg1a*t01, sg1b*t11);
            ((float*)&u1L[2][0])[l]=pack2(sg1a*t02, sg1b*t12);
        }
        // S6: Jf[d][rowblk] = dtan * (V2 @ u1[d]) — rotated LDS, fully lane-local output
        float J00,J01,J02,J10,J11,J12,J20,J21,J22;
        {
            float t00=0,t01=0,t02=0,t10=0,t11=0,t12=0,t20=0,t21=0,t22=0; // t{dir}{rowblk}
            #pragma unroll
            for (int j=0;j<16;j++){
                const int c = (j + dl) & 15;
                float4 w0 = v2L[l*16 + c];
                float4 w1 = v2L[(64+l)*16 + c];
                float4 w2 = v2L[(128+l)*16 + c];
                float4 q0=u1L[0][c], q1=u1L[1][c], q2=u1L[2][c];
                t00=dot2q(w0,q0,t00); t01=dot2q(w1,q0,t01); t02=dot2q(w2,q0,t02);
                t10=dot2q(w0,q1,t10); t11=dot2q(w1,q1,t11); t12=dot2q(w2,q1,t12);
                t20=dot2q(w0,q2,t20); t21=dot2q(w1,q2,t21); t22=dot2q(w2,q2,t22);
            }
            J00=dt0*t00; J01=dt1*t01; J02=dt2*t02;
            J10=dt0*t10; J11=dt1*t11; J12=dt2*t12;
            J20=dt0*t20; J21=dt1*t21; J22=dt2*t22;
        }
        // S7 + Heun (lane-local, fp32)
        float kk = mm0*s0 + mm1*s1 + mm2*s2
                 + s3*(J01-J10) + s4*(J02-J20) + s5*(J12-J21);
        if (first){
            k1 = kk;
            float y2v = y + dt*kk;
            ((_Float16*)y2aL)[l] = (_Float16)y2v;
        } else {
            y = y + 0.5f*dt*(k1 + kk);
            ((_Float16*)yaL)[l] = (_Float16)y;
        }
    };

    // ---- Heun scan ----
    for (int step=0; step<NSTEP; ++step) {
        const int w = step >> 3;
        const float s0=slopesSh[w][0], s1=slopesSh[w][1], s2=slopesSh[w][2],
                    s3=slopesSh[w][3], s4=slopesSh[w][4], s5=slopesSh[w][5];
        const float dt = dtsSh[step];
        // projection of current y (lanes 0..31; fp16 R & y, rotated R reads)
        if (l < OUTD) {
            float pa=0.f, pb=0.f;
            #pragma unroll
            for (int j=0;j<8;j++){
                const int c = (j + dlR) & 7;
                float4 wv = rL[l*8 + c];
                float4 av = yaL[c];
                if (j<4) pa=dot2q(wv,av,pa); else pb=dot2q(wv,av,pb);
            }
            out[(size_t)(b*TT + step)*OUTD + l] = tanh_f(pa+pb+rbp);
        }
        Feval(yaL,  true,  dt, s0,s1,s2,s3,s4,s5);
        Feval(y2aL, false, dt, s0,s1,s2,s3,s4,s5);
    }
    // final row T-1
    if (l < OUTD) {
        float pa=0.f, pb=0.f;
        #pragma unroll
        for (int j=0;j<8;j++){
            const int c = (j + dlR) & 7;
            float4 wv = rL[l*8 + c];
            float4 av = yaL[c];
            if (j<4) pa=dot2q(wv,av,pa); else pb=dot2q(wv,av,pb);
        }
        out[(size_t)(b*TT + NSTEP)*OUTD + l] = tanh_f(pa+pb+rbp);
    }
}

extern "C" void kernel_launch(void* const* d_in, const int* in_sizes, int n_in,
                              void* d_out, int out_size, void* d_ws, size_t ws_size,
                              hipStream_t stream) {
    const float* ts = (const float*)d_in[0];
    const float* x  = (const float*)d_in[1];
    const float* W0 = (const float*)d_in[2];
    const float* b0 = (const float*)d_in[3];
    const float* W1 = (const float*)d_in[4];
    const float* b1 = (const float*)d_in[5];
    const float* W2 = (const float*)d_in[6];
    const float* b2 = (const float*)d_in[7];
    const float* V0 = (const float*)d_in[8];
    const float* c0 = (const float*)d_in[9];
    const float* V1 = (const float*)d_in[10];
    const float* c1 = (const float*)d_in[11];
    const float* V2 = (const float*)d_in[12];
    const float* c2 = (const float*)d_in[13];
    const float* R  = (const float*)d_in[14];
    const float* rb = (const float*)d_in[15];
    float* out = (float*)d_out;

    ncde_solve<<<dim3(BB), dim3(64), 0, stream>>>(
        ts, x, W0, b0, W1, b1, W2, b2, V0, c0, V1, c1, V2, c2, R, rb, out);
}